// Round 2
// baseline (818.528 us; speedup 1.0000x reference)
//
#include <hip/hip_runtime.h>
#include <stdint.h>

typedef unsigned long long u64;
typedef unsigned int u32;

#define DD 128          // node_dim
#define EAD 16          // edge_attr dim
#define R2C 272.25f     // RADIUS^2
#define NBINS 4096
#define LCAP 4096       // per-center candidate list capacity
#define CANDCAP 512     // per-center collected-candidate capacity
#define THRESHV 0.1
#define TN 128          // nodes per K1 block

// ---------------- workspace layout (bytes) ----------------
#define NPAD 100096
#define LIST_BYTES ((size_t)256 * LCAP * 8)         // u64[256][LCAP] = 8 MiB
#define DBL_OFF    LIST_BYTES
// double indices within the double region:
#define DU    0                   // [128]  W_neigh @ lin_w
#define DR    128                 // [128]  W_root  @ lin_w
#define DV    256                 // [16]   W_edge  @ lin_w
#define DCC   272                 // [256]  per-center |c|^2 (fp64)
#define DROOT 528                 // [NPAD] x . r
#define DA    (528 + NPAD)        // [NPAD] x . u
#define DAGG  (528 + 2*NPAD)      // [NPAD] aggregate (zeroed)
#define DEND  (528 + 3*NPAD)
#define INT_OFF (DBL_OFF + (size_t)DEND * 8)
#define CCT_B   0                 // float2[256] (ccf, T)
#define MASK_B  2048              // u32[3200] in_nb bitmask (zeroed)
#define CNT_B   (2048 + 12800)    // int[256] candidate counters (zeroed)
#define HNB_B   (2048 + 12800 + 1024) // int[256] has_neighbor (zeroed)
#define INT_BYTES (2048 + 12800 + 1024 + 1024)
#define ZERO_OFF   (DBL_OFF + (size_t)DAGG * 8)
#define ZERO_BYTES ((size_t)NPAD * 8 + INT_BYTES)   // agg64 + (cct) + mask + cnt + hnb
#define WS_NEED    (INT_OFF + INT_BYTES)

__device__ __forceinline__ float fma4(float4 a, float4 b, float acc) {
  acc = fmaf(a.x, b.x, acc); acc = fmaf(a.y, b.y, acc);
  acc = fmaf(a.z, b.z, acc); acc = fmaf(a.w, b.w, acc);
  return acc;
}

// fp32 d2 (fallback path only; self-consistent within K2)
__device__ float d2f32(const float* __restrict__ center, const float* __restrict__ x,
                       int c, int n, float ccv) {
  float dt = 0.f, xx = 0.f;
  for (int j = 0; j < DD; j += 4) {
    float4 xv = *(const float4*)(x + (size_t)n*DD + j);
    float4 cv = *(const float4*)(center + (size_t)c*DD + j);
    dt = fma4(xv, cv, dt); xx = fma4(xv, xv, xx);
  }
  return (ccv + xx) - 2.0f*dt;
}

// ---------- KA: precompute u, r, v (fp64), per-center cc (fp64) + fp32 (cc,T) ----------
__global__ void ka_pre(const float* __restrict__ Wr, const float* __restrict__ Wn,
                       const float* __restrict__ We, const float* __restrict__ lw,
                       const float* __restrict__ center,
                       double* __restrict__ dbl, float2* __restrict__ cct, int M) {
  int t = threadIdx.x;
  if (blockIdx.x == 0) {
    if (t < DD) {
      double su = 0.0, sr = 0.0;
      for (int j = 0; j < DD; ++j) {
        double l = (double)lw[j];
        su = fma((double)Wn[(size_t)t*DD + j], l, su);
        sr = fma((double)Wr[(size_t)t*DD + j], l, sr);
      }
      dbl[DU + t] = su; dbl[DR + t] = sr;
    } else if (t < DD + EAD) {
      int k = t - DD; double sv = 0.0;
      for (int j = 0; j < DD; ++j)
        sv = fma((double)We[(size_t)k*DD + j], (double)lw[j], sv);
      dbl[DV + k] = sv;
    }
  } else {
    if (t < M) {
      double s = 0.0;
      for (int j = 0; j < DD; ++j) {
        double cv = (double)center[(size_t)t*DD + j];
        s = fma(cv, cv, s);
      }
      dbl[DCC + t] = s;
      float ccf = (float)s;
      // candidate threshold: mean cc+D, sd = sqrt(2D+4cc); z=2.25 -> ~1200 candidates,
      // >=25 sigma above the top-64 cutoff -> provably complete in practice; fallback covers rest
      float T = ccf + (float)DD - 2.25f * sqrtf(2.0f*(float)DD + 4.0f*ccf);
      T = fminf(T, R2C);
      cct[t] = make_float2(ccf, T);
    }
  }
}

// ---------- K1: fp32 distance pass + candidate capture + fp64 per-node scalars ----------
#define SWZ(n, dc) ((n) ^ ((dc) & 7))

__launch_bounds__(256, 2)
__global__ void k1_d2(const float* __restrict__ x, const float* __restrict__ center,
                      const double* __restrict__ dbl, const float2* __restrict__ cct,
                      double* __restrict__ root64, double* __restrict__ a64,
                      int* __restrict__ cnt, u64* __restrict__ list, int N, int M) {
  __shared__ float4 lds4[32 * TN];   // 64 KiB, [dchunk][node] XOR-swizzled
  const int tid = threadIdx.x;
  const int nbase = blockIdx.x * TN;

  #pragma unroll
  for (int i = 0; i < 16; ++i) {
    int f = i*256 + tid;               // 4096 float4
    int node = f >> 5, dc = f & 31;
    float4 val = make_float4(0.f,0.f,0.f,0.f);
    int gn = nbase + node;
    if (gn < N) val = *(const float4*)(x + (size_t)gn*DD + dc*4);
    lds4[dc*TN + SWZ(node, dc)] = val;
  }
  __syncthreads();

  const int nloc = tid & (TN-1);
  const int gnode = nbase + nloc;

  // per-node xx (fp32, all threads); root/a (fp64, first half only)
  float xxv = 0.f;
  double ra = 0.0, aa = 0.0;
  const bool wr = (tid < TN) && (gnode < N);
  for (int dc = 0; dc < 32; ++dc) {
    float4 xv = lds4[dc*TN + SWZ(nloc, dc)];
    xxv = fma4(xv, xv, xxv);
    if (wr) {
      const float* pv = (const float*)&xv;
      #pragma unroll
      for (int q = 0; q < 4; ++q) {
        double dx = (double)pv[q];
        ra = fma(dx, dbl[DR + dc*4 + q], ra);
        aa = fma(dx, dbl[DU + dc*4 + q], aa);
      }
    }
  }
  if (wr) { root64[gnode] = ra; a64[gnode] = aa; }

  // each half of the block covers half the centers, 16-center register tiles
  const int chalf = tid >> 7;
  const int nchunks = M >> 5;          // 8 chunks of 16 per half
  for (int c8 = 0; c8 < nchunks; ++c8) {
    const int cb = __builtin_amdgcn_readfirstlane(chalf * (M >> 1) + c8 * 16);
    float acc[16];
    #pragma unroll
    for (int j = 0; j < 16; ++j) acc[j] = 0.f;
    for (int dc = 0; dc < 32; ++dc) {
      float4 xv = lds4[dc*TN + SWZ(nloc, dc)];
      #pragma unroll
      for (int j = 0; j < 16; ++j) {
        float4 cv = *(const float4*)(center + (size_t)(cb + j)*DD + dc*4); // uniform -> scalar load
        acc[j] = fma4(xv, cv, acc[j]);
      }
    }
    if (gnode < N) {
      #pragma unroll
      for (int j = 0; j < 16; ++j) {
        float2 ct = cct[cb + j];
        float val = (ct.x + xxv) - 2.0f*acc[j];
        if (val <= ct.y) {
          int slot = atomicAdd(&cnt[cb + j], 1);
          if (slot < LCAP)
            list[(size_t)(cb + j)*LCAP + slot] =
              ((u64)__float_as_uint(val) << 32) | (u32)gnode;
        }
      }
    }
  }
}

// ---------- K2: exact per-center top-64 (fp64 re-rank of candidates) ----------
__launch_bounds__(256)
__global__ void k2_sel(const float* __restrict__ x, const float* __restrict__ center,
                       const double* __restrict__ dbl, const float2* __restrict__ cct,
                       u32* __restrict__ mask, int* __restrict__ hnb,
                       const u64* __restrict__ list, const int* __restrict__ cnt, int N) {
  const int c = blockIdx.x, tid = threadIdx.x;
  __shared__ u32 hist[NBINS];
  __shared__ double dval[CANDCAP];
  __shared__ int    dnode[CANDCAP];
  __shared__ u32 spart[256];
  __shared__ int shW, shB, shQ;

  for (int i = tid; i < NBINS; i += 256) hist[i] = 0u;
  if (tid == 0) { shW = 0; shB = 0x7ffffff; shQ = 0; }
  __syncthreads();

  const float2 ct = cct[c];
  const int C = cnt[c];
  const bool fast = (C >= 64 && C <= LCAP);
  const float bscale = (float)NBINS / R2C;

  if (fast) {
    for (int i = tid; i < C; i += 256) {
      float val = __uint_as_float((u32)(list[(size_t)c*LCAP + i] >> 32));
      int b = (int)(val * bscale); b = min(NBINS-1, max(0, b));
      atomicAdd(&hist[b], 1u);
    }
  } else {
    int w = 0;
    for (int n = tid; n < N; n += 256) {
      float val = d2f32(center, x, c, n, ct.x);
      if (val <= R2C) {
        ++w;
        int b = (int)(val * bscale); b = min(NBINS-1, max(0, b));
        atomicAdd(&hist[b], 1u);
      }
    }
    atomicAdd(&shW, w);
  }
  __syncthreads();
  const int W = fast ? 0x7fffffff : shW;
  if (W == 0) return;                  // has_nb stays 0
  const int Rk = min(64, W);

  // block-wide scan of hist -> first bin B with cum >= Rk
  u32 loc[16]; u32 psum = 0;
  const int b0 = tid * 16;
  #pragma unroll
  for (int k = 0; k < 16; ++k) { loc[k] = hist[b0 + k]; psum += loc[k]; }
  spart[tid] = psum; __syncthreads();
  for (int off = 1; off < 256; off <<= 1) {
    u32 vv = (tid >= off) ? spart[tid - off] : 0u;
    __syncthreads(); spart[tid] += vv; __syncthreads();
  }
  u32 run = spart[tid] - psum;
  int Bl = 0x7ffffff;
  #pragma unroll
  for (int k = 0; k < 16; ++k) { run += loc[k]; if ((int)run >= Rk && Bl == 0x7ffffff) Bl = b0 + k; }
  if (Bl != 0x7ffffff) atomicMin(&shB, Bl);
  __syncthreads();
  const int Bcol = min(shB + 2, NBINS - 1);  // +2 bins of slack >> fp32 noise

  // collect candidate nodes with bin <= Bcol
  if (fast) {
    for (int i = tid; i < C; i += 256) {
      u64 e = list[(size_t)c*LCAP + i];
      float val = __uint_as_float((u32)(e >> 32));
      int b = (int)(val * bscale); b = min(NBINS-1, max(0, b));
      if (b <= Bcol) { int s = atomicAdd(&shQ, 1); if (s < CANDCAP) dnode[s] = (int)(u32)e; }
    }
  } else {
    for (int n = tid; n < N; n += 256) {
      float val = d2f32(center, x, c, n, ct.x);
      if (val <= R2C) {
        int b = (int)(val * bscale); b = min(NBINS-1, max(0, b));
        if (b <= Bcol) { int s = atomicAdd(&shQ, 1); if (s < CANDCAP) dnode[s] = n; }
      }
    }
  }
  __syncthreads();
  const int Q = min(shQ, CANDCAP);

  // fp64 re-rank: exact values for collected candidates
  const double ccd = dbl[DCC + c];
  for (int i = tid; i < Q; i += 256) {
    int n = dnode[i];
    double dt = 0.0, xx = 0.0;
    for (int j = 0; j < DD; ++j) {
      double dx = (double)x[(size_t)n*DD + j];
      dt = fma(dx, (double)center[(size_t)c*DD + j], dt);
      xx = fma(dx, dx, xx);
    }
    dval[i] = (ccd + xx) - 2.0*dt;
  }
  __syncthreads();

  // exact rank-select: rank_i = #{j : (val_j, node_j) < (val_i, node_i)}; keep rank < Rk
  for (int i = tid; i < Q; i += 256) {
    double vi = dval[i]; int ni = dnode[i];
    int rank = 0;
    for (int j = 0; j < Q; ++j) {
      double vj = dval[j];
      rank += (vj < vi) || (vj == vi && dnode[j] < ni);
    }
    if (rank < Rk) atomicOr(&mask[(u32)ni >> 5], 1u << (ni & 31));
  }
  if (tid == 0) hnb[c] = 1;
}

// ---------- K3: edge pass (fp64 scalar messages, edge_attr read only when kept) ----------
__global__ void k3_edge(const int* __restrict__ ei, const float* __restrict__ eattr,
                        const double* __restrict__ dbl, const u32* __restrict__ mask,
                        double* __restrict__ agg, const double* __restrict__ a64, int E) {
  int e = blockIdx.x*256 + threadIdx.x;
  if (e >= E) return;
  int s = ei[e], d = ei[E + e];
  u32 ks = (mask[(u32)s >> 5] >> (s & 31)) & 1u;
  u32 kd = (mask[(u32)d >> 5] >> (d & 31)) & 1u;
  if (!(ks & kd)) return;
  const float* ep = eattr + (size_t)e * EAD;
  double ea = 0.0;
  #pragma unroll
  for (int k = 0; k < EAD; ++k) ea = fma((double)ep[k], dbl[DV + k], ea);
  atomicAdd(&agg[d], a64[s] + ea);
}

// ---------- K4: gate + int32 output ----------
__global__ void k4_out(const double* __restrict__ root64, const double* __restrict__ agg64,
                       const u32* __restrict__ mask, const int* __restrict__ hnb,
                       const float* __restrict__ lb, int* __restrict__ out, int N, int M) {
  int n = blockIdx.x*256 + threadIdx.x;
  if (n >= N) return;
  double pre = root64[n] + agg64[n] + (double)lb[0];
  bool selb = ((mask[n >> 5] >> (n & 31)) & 1u) != 0u;
  if (!selb && n < M) selb = hnb[n] != 0;
  out[n] = (selb && pre > THRESHV) ? 1 : 0;
}

extern "C" void kernel_launch(void* const* d_in, const int* in_sizes, int n_in,
                              void* d_out, int out_size, void* d_ws, size_t ws_size,
                              hipStream_t stream) {
  const float* x      = (const float*)d_in[0];
  const int*   ei     = (const int*)d_in[1];
  const float* eattr  = (const float*)d_in[2];
  const float* center = (const float*)d_in[3];
  const float* Wr     = (const float*)d_in[4];
  const float* Wn     = (const float*)d_in[5];
  const float* We     = (const float*)d_in[6];
  const float* lw     = (const float*)d_in[7];
  const float* lb     = (const float*)d_in[8];
  int* out = (int*)d_out;

  char* wsb = (char*)d_ws;
  u64*    list   = (u64*)(wsb);
  double* dbl    = (double*)(wsb + DBL_OFF);
  float2* cct    = (float2*)(wsb + INT_OFF + CCT_B);
  u32*    mask   = (u32*)(wsb + INT_OFF + MASK_B);
  int*    cnt    = (int*)(wsb + INT_OFF + CNT_B);
  int*    hnb    = (int*)(wsb + INT_OFF + HNB_B);
  double* root64 = dbl + DROOT;
  double* a64    = dbl + DA;
  double* agg64  = dbl + DAGG;

  const int N = in_sizes[0] / DD;      // 100000
  const int E = in_sizes[1] / 2;       // 1000000
  const int M = in_sizes[3] / DD;      // 256
  if (N > NPAD || M > 256 || ws_size < WS_NEED) return;
  (void)n_in; (void)out_size;

  // zero agg64 + mask + cnt + hnb (one contiguous region; cct rewritten by ka_pre)
  hipMemsetAsync(wsb + ZERO_OFF, 0, ZERO_BYTES, stream);

  ka_pre<<<2, 256, 0, stream>>>(Wr, Wn, We, lw, center, dbl, cct, M);
  k1_d2<<<(N + TN - 1)/TN, 256, 0, stream>>>(x, center, dbl, cct, root64, a64, cnt, list, N, M);
  k2_sel<<<M, 256, 0, stream>>>(x, center, dbl, cct, mask, hnb, list, cnt, N);
  k3_edge<<<(E + 255)/256, 256, 0, stream>>>(ei, eattr, dbl, mask, agg64, a64, E);
  k4_out<<<(N + 255)/256, 256, 0, stream>>>(root64, agg64, mask, hnb, lb, out, N, M);
}

// Round 3
// 671.493 us; speedup vs baseline: 1.2190x; 1.2190x over previous
//
#include <hip/hip_runtime.h>
#include <stdint.h>

typedef unsigned long long u64;
typedef unsigned int u32;

#define DD 128          // node_dim
#define EAD 16          // edge_attr dim
#define R2C 272.25f     // RADIUS^2
#define NBINS 4096
#define LCAP 4096       // per-center candidate list capacity
#define CANDCAP 512     // per-center collected-candidate capacity
#define THRESHV 0.1
#define TN 128          // nodes per K1 block

// ---------------- workspace layout (bytes) ----------------
#define NPAD 100096
#define LIST_BYTES ((size_t)256 * LCAP * 8)         // u64[256][LCAP] = 8 MiB
#define DBL_OFF    LIST_BYTES
// double indices within the double region:
#define DU    0                   // [128]  W_neigh @ lin_w
#define DR    128                 // [128]  W_root  @ lin_w
#define DV    256                 // [16]   W_edge  @ lin_w
#define DCC   272                 // [256]  per-center |c|^2 (fp64)
#define DROOT 528                 // [NPAD] x . r
#define DA    (528 + NPAD)        // [NPAD] x . u
#define DAGG  (528 + 2*NPAD)      // [NPAD] aggregate (zeroed)
#define DEND  (528 + 3*NPAD)
#define INT_OFF (DBL_OFF + (size_t)DEND * 8)
#define CCT_B   0                 // float2[256] (ccf, T)
#define MASK_B  2048              // u32[3200] in_nb bitmask (zeroed)
#define CNT_B   (2048 + 12800)    // int[256] candidate counters (zeroed)
#define HNB_B   (2048 + 12800 + 1024) // int[256] has_neighbor (zeroed)
#define INT_BYTES (2048 + 12800 + 1024 + 1024)
#define ZERO_OFF   (DBL_OFF + (size_t)DAGG * 8)
#define ZERO_BYTES ((size_t)NPAD * 8 + INT_BYTES)   // agg64 + (cct) + mask + cnt + hnb
#define WS_NEED    (INT_OFF + INT_BYTES)

__device__ __forceinline__ float fma4(float4 a, float4 b, float acc) {
  acc = fmaf(a.x, b.x, acc); acc = fmaf(a.y, b.y, acc);
  acc = fmaf(a.z, b.z, acc); acc = fmaf(a.w, b.w, acc);
  return acc;
}

// fp32 d2 (fallback path only; self-consistent within K2)
__device__ float d2f32(const float* __restrict__ center, const float* __restrict__ x,
                       int c, int n, float ccv) {
  float dt = 0.f, xx = 0.f;
  for (int j = 0; j < DD; j += 4) {
    float4 xv = *(const float4*)(x + (size_t)n*DD + j);
    float4 cv = *(const float4*)(center + (size_t)c*DD + j);
    dt = fma4(xv, cv, dt); xx = fma4(xv, xv, xx);
  }
  return (ccv + xx) - 2.0f*dt;
}

// ---------- KA: precompute u, r, v (fp64), per-center cc (fp64) + fp32 (cc,T) ----------
__global__ void ka_pre(const float* __restrict__ Wr, const float* __restrict__ Wn,
                       const float* __restrict__ We, const float* __restrict__ lw,
                       const float* __restrict__ center,
                       double* __restrict__ dbl, float2* __restrict__ cct, int M) {
  int t = threadIdx.x;
  if (blockIdx.x == 0) {
    if (t < DD) {
      double su = 0.0, sr = 0.0;
      for (int j = 0; j < DD; ++j) {
        double l = (double)lw[j];
        su = fma((double)Wn[(size_t)t*DD + j], l, su);
        sr = fma((double)Wr[(size_t)t*DD + j], l, sr);
      }
      dbl[DU + t] = su; dbl[DR + t] = sr;
    } else if (t < DD + EAD) {
      int k = t - DD; double sv = 0.0;
      for (int j = 0; j < DD; ++j)
        sv = fma((double)We[(size_t)k*DD + j], (double)lw[j], sv);
      dbl[DV + k] = sv;
    }
  } else {
    if (t < M) {
      double s = 0.0;
      for (int j = 0; j < DD; ++j) {
        double cv = (double)center[(size_t)t*DD + j];
        s = fma(cv, cv, s);
      }
      dbl[DCC + t] = s;
      float ccf = (float)s;
      // candidate threshold: mean cc+D, sd = sqrt(2D+4cc); z=2.25 -> ~1200 candidates,
      // far above the top-64 cutoff; fallback covers any miss
      float T = ccf + (float)DD - 2.25f * sqrtf(2.0f*(float)DD + 4.0f*ccf);
      T = fminf(T, R2C);
      cct[t] = make_float2(ccf, T);
    }
  }
}

// ---------- K1: fp32 distance pass (x tile + center chunk both in LDS) ----------
#define SWZ(n, dc) ((n) ^ ((dc) & 7))

__launch_bounds__(256, 2)
__global__ void k1_d2(const float* __restrict__ x, const float* __restrict__ center,
                      const double* __restrict__ dbl, const float2* __restrict__ cct,
                      double* __restrict__ root64, double* __restrict__ a64,
                      int* __restrict__ cnt, u64* __restrict__ list, int N, int M) {
  __shared__ float4 ldsx[32 * TN];   // 64 KiB, [dchunk][node] XOR-swizzled
  __shared__ float4 ldsc[32 * 32];   // 16 KiB, 32 centers x 128 dims, [row][dc] linear
  const int tid = threadIdx.x;
  const int nbase = blockIdx.x * TN;
  const int Mhalf = M >> 1;

  #pragma unroll
  for (int i = 0; i < 16; ++i) {
    int f = i*256 + tid;               // 4096 float4
    int node = f >> 5, dc = f & 31;
    float4 val = make_float4(0.f,0.f,0.f,0.f);
    int gn = nbase + node;
    if (gn < N) val = *(const float4*)(x + (size_t)gn*DD + dc*4);
    ldsx[dc*TN + SWZ(node, dc)] = val;
  }
  __syncthreads();

  const int nloc = tid & (TN-1);
  const int gnode = nbase + nloc;

  // per-node xx (fp32, all threads); root/a (fp64, first half only)
  float xxv = 0.f;
  double ra = 0.0, aa = 0.0;
  const bool wr = (tid < TN) && (gnode < N);
  for (int dc = 0; dc < 32; ++dc) {
    float4 xv = ldsx[dc*TN + SWZ(nloc, dc)];
    xxv = fma4(xv, xv, xxv);
    if (wr) {
      const float* pv = (const float*)&xv;
      #pragma unroll
      for (int q = 0; q < 4; ++q) {
        double dx = (double)pv[q];
        ra = fma(dx, dbl[DR + dc*4 + q], ra);
        aa = fma(dx, dbl[DU + dc*4 + q], aa);
      }
    }
  }
  if (wr) { root64[gnode] = ra; a64[gnode] = aa; }

  // per chunk iter: stage 32 centers (16 for each half-block) into LDS, then all-LDS FMA loop
  const int chalf = tid >> 7;
  const int crow = chalf * 16;         // this half's rows within ldsc
  const int nchunks = Mhalf >> 4;      // 8 when M=256
  for (int c8 = 0; c8 < nchunks; ++c8) {
    // stage: 1024 float4, 4 per thread (coalesced global, linear LDS)
    #pragma unroll
    for (int q = 0; q < 4; ++q) {
      int f = q*256 + tid;
      int row = f >> 5, col = f & 31;
      int grow = (row < 16) ? (c8*16 + row) : (Mhalf + c8*16 + (row - 16));
      ldsc[row*32 + col] = *(const float4*)(center + (size_t)grow*DD + col*4);
    }
    __syncthreads();

    const int cb = __builtin_amdgcn_readfirstlane(chalf * Mhalf + c8 * 16);
    float acc[16];
    #pragma unroll
    for (int j = 0; j < 16; ++j) acc[j] = 0.f;
    for (int dc = 0; dc < 32; ++dc) {
      float4 xv = ldsx[dc*TN + SWZ(nloc, dc)];
      #pragma unroll
      for (int j = 0; j < 16; ++j) {
        float4 cv = ldsc[(crow + j)*32 + dc];   // wave-uniform -> LDS broadcast
        acc[j] = fma4(xv, cv, acc[j]);
      }
    }
    if (gnode < N) {
      #pragma unroll
      for (int j = 0; j < 16; ++j) {
        float2 ct = cct[cb + j];
        float val = (ct.x + xxv) - 2.0f*acc[j];
        if (val <= ct.y) {
          int slot = atomicAdd(&cnt[cb + j], 1);
          if (slot < LCAP)
            list[(size_t)(cb + j)*LCAP + slot] =
              ((u64)__float_as_uint(val) << 32) | (u32)gnode;
        }
      }
    }
    __syncthreads();   // compute done before next stage overwrites ldsc
  }
}

// ---------- K2: exact per-center top-64 (fp64 re-rank of candidates) ----------
__launch_bounds__(256)
__global__ void k2_sel(const float* __restrict__ x, const float* __restrict__ center,
                       const double* __restrict__ dbl, const float2* __restrict__ cct,
                       u32* __restrict__ mask, int* __restrict__ hnb,
                       const u64* __restrict__ list, const int* __restrict__ cnt, int N) {
  const int c = blockIdx.x, tid = threadIdx.x;
  __shared__ u32 hist[NBINS];
  __shared__ double dval[CANDCAP];
  __shared__ int    dnode[CANDCAP];
  __shared__ u32 spart[256];
  __shared__ int shW, shB, shQ;

  for (int i = tid; i < NBINS; i += 256) hist[i] = 0u;
  if (tid == 0) { shW = 0; shB = 0x7ffffff; shQ = 0; }
  __syncthreads();

  const float2 ct = cct[c];
  const int C = cnt[c];
  const bool fast = (C >= 64 && C <= LCAP);
  const float bscale = (float)NBINS / R2C;

  if (fast) {
    for (int i = tid; i < C; i += 256) {
      float val = __uint_as_float((u32)(list[(size_t)c*LCAP + i] >> 32));
      int b = (int)(val * bscale); b = min(NBINS-1, max(0, b));
      atomicAdd(&hist[b], 1u);
    }
  } else {
    int w = 0;
    for (int n = tid; n < N; n += 256) {
      float val = d2f32(center, x, c, n, ct.x);
      if (val <= R2C) {
        ++w;
        int b = (int)(val * bscale); b = min(NBINS-1, max(0, b));
        atomicAdd(&hist[b], 1u);
      }
    }
    atomicAdd(&shW, w);
  }
  __syncthreads();
  const int W = fast ? 0x7fffffff : shW;
  if (W == 0) return;                  // has_nb stays 0
  const int Rk = min(64, W);

  // block-wide scan of hist -> first bin B with cum >= Rk
  u32 loc[16]; u32 psum = 0;
  const int b0 = tid * 16;
  #pragma unroll
  for (int k = 0; k < 16; ++k) { loc[k] = hist[b0 + k]; psum += loc[k]; }
  spart[tid] = psum; __syncthreads();
  for (int off = 1; off < 256; off <<= 1) {
    u32 vv = (tid >= off) ? spart[tid - off] : 0u;
    __syncthreads(); spart[tid] += vv; __syncthreads();
  }
  u32 run = spart[tid] - psum;
  int Bl = 0x7ffffff;
  #pragma unroll
  for (int k = 0; k < 16; ++k) { run += loc[k]; if ((int)run >= Rk && Bl == 0x7ffffff) Bl = b0 + k; }
  if (Bl != 0x7ffffff) atomicMin(&shB, Bl);
  __syncthreads();
  const int Bcol = min(shB + 2, NBINS - 1);  // +2 bins of slack >> fp32 noise

  // collect candidate nodes with bin <= Bcol
  if (fast) {
    for (int i = tid; i < C; i += 256) {
      u64 e = list[(size_t)c*LCAP + i];
      float val = __uint_as_float((u32)(e >> 32));
      int b = (int)(val * bscale); b = min(NBINS-1, max(0, b));
      if (b <= Bcol) { int s = atomicAdd(&shQ, 1); if (s < CANDCAP) dnode[s] = (int)(u32)e; }
    }
  } else {
    for (int n = tid; n < N; n += 256) {
      float val = d2f32(center, x, c, n, ct.x);
      if (val <= R2C) {
        int b = (int)(val * bscale); b = min(NBINS-1, max(0, b));
        if (b <= Bcol) { int s = atomicAdd(&shQ, 1); if (s < CANDCAP) dnode[s] = n; }
      }
    }
  }
  __syncthreads();
  const int Q = min(shQ, CANDCAP);

  // fp64 re-rank: exact values for collected candidates
  const double ccd = dbl[DCC + c];
  for (int i = tid; i < Q; i += 256) {
    int n = dnode[i];
    double dt = 0.0, xx = 0.0;
    for (int j = 0; j < DD; ++j) {
      double dx = (double)x[(size_t)n*DD + j];
      dt = fma(dx, (double)center[(size_t)c*DD + j], dt);
      xx = fma(dx, dx, xx);
    }
    dval[i] = (ccd + xx) - 2.0*dt;
  }
  __syncthreads();

  // exact rank-select: rank_i = #{j : (val_j, node_j) < (val_i, node_i)}; keep rank < Rk
  for (int i = tid; i < Q; i += 256) {
    double vi = dval[i]; int ni = dnode[i];
    int rank = 0;
    for (int j = 0; j < Q; ++j) {
      double vj = dval[j];
      rank += (vj < vi) || (vj == vi && dnode[j] < ni);
    }
    if (rank < Rk) atomicOr(&mask[(u32)ni >> 5], 1u << (ni & 31));
  }
  if (tid == 0) hnb[c] = 1;
}

// ---------- K3: edge pass (fp64 scalar messages, edge_attr read only when kept) ----------
__global__ void k3_edge(const int* __restrict__ ei, const float* __restrict__ eattr,
                        const double* __restrict__ dbl, const u32* __restrict__ mask,
                        double* __restrict__ agg, const double* __restrict__ a64, int E) {
  int e = blockIdx.x*256 + threadIdx.x;
  if (e >= E) return;
  int s = ei[e], d = ei[E + e];
  u32 ks = (mask[(u32)s >> 5] >> (s & 31)) & 1u;
  u32 kd = (mask[(u32)d >> 5] >> (d & 31)) & 1u;
  if (!(ks & kd)) return;
  const float* ep = eattr + (size_t)e * EAD;
  double ea = 0.0;
  #pragma unroll
  for (int k = 0; k < EAD; ++k) ea = fma((double)ep[k], dbl[DV + k], ea);
  atomicAdd(&agg[d], a64[s] + ea);
}

// ---------- K4: gate + int32 output ----------
__global__ void k4_out(const double* __restrict__ root64, const double* __restrict__ agg64,
                       const u32* __restrict__ mask, const int* __restrict__ hnb,
                       const float* __restrict__ lb, int* __restrict__ out, int N, int M) {
  int n = blockIdx.x*256 + threadIdx.x;
  if (n >= N) return;
  double pre = root64[n] + agg64[n] + (double)lb[0];
  bool selb = ((mask[n >> 5] >> (n & 31)) & 1u) != 0u;
  if (!selb && n < M) selb = hnb[n] != 0;
  out[n] = (selb && pre > THRESHV) ? 1 : 0;
}

extern "C" void kernel_launch(void* const* d_in, const int* in_sizes, int n_in,
                              void* d_out, int out_size, void* d_ws, size_t ws_size,
                              hipStream_t stream) {
  const float* x      = (const float*)d_in[0];
  const int*   ei     = (const int*)d_in[1];
  const float* eattr  = (const float*)d_in[2];
  const float* center = (const float*)d_in[3];
  const float* Wr     = (const float*)d_in[4];
  const float* Wn     = (const float*)d_in[5];
  const float* We     = (const float*)d_in[6];
  const float* lw     = (const float*)d_in[7];
  const float* lb     = (const float*)d_in[8];
  int* out = (int*)d_out;

  char* wsb = (char*)d_ws;
  u64*    list   = (u64*)(wsb);
  double* dbl    = (double*)(wsb + DBL_OFF);
  float2* cct    = (float2*)(wsb + INT_OFF + CCT_B);
  u32*    mask   = (u32*)(wsb + INT_OFF + MASK_B);
  int*    cnt    = (int*)(wsb + INT_OFF + CNT_B);
  int*    hnb    = (int*)(wsb + INT_OFF + HNB_B);
  double* root64 = dbl + DROOT;
  double* a64    = dbl + DA;
  double* agg64  = dbl + DAGG;

  const int N = in_sizes[0] / DD;      // 100000
  const int E = in_sizes[1] / 2;       // 1000000
  const int M = in_sizes[3] / DD;      // 256
  if (N > NPAD || M > 256 || (M & 31) || ws_size < WS_NEED) return;
  (void)n_in; (void)out_size;

  // zero agg64 + mask + cnt + hnb (one contiguous region; cct rewritten by ka_pre)
  hipMemsetAsync(wsb + ZERO_OFF, 0, ZERO_BYTES, stream);

  ka_pre<<<2, 256, 0, stream>>>(Wr, Wn, We, lw, center, dbl, cct, M);
  k1_d2<<<(N + TN - 1)/TN, 256, 0, stream>>>(x, center, dbl, cct, root64, a64, cnt, list, N, M);
  k2_sel<<<M, 256, 0, stream>>>(x, center, dbl, cct, mask, hnb, list, cnt, N);
  k3_edge<<<(E + 255)/256, 256, 0, stream>>>(ei, eattr, dbl, mask, agg64, a64, E);
  k4_out<<<(N + 255)/256, 256, 0, stream>>>(root64, agg64, mask, hnb, lb, out, N, M);
}

// Round 4
// 426.043 us; speedup vs baseline: 1.9212x; 1.5761x over previous
//
#include <hip/hip_runtime.h>
#include <stdint.h>

typedef unsigned long long u64;
typedef unsigned int u32;
typedef __attribute__((ext_vector_type(8))) short bf16x8;
typedef __attribute__((ext_vector_type(4))) float f32x4;

#define DD 128          // node_dim
#define EAD 16          // edge_attr dim
#define R2C 272.25f     // RADIUS^2
#define NBINS 4096
#define LCAP 4096       // per-center candidate list capacity
#define CANDCAP 512     // per-center collected-candidate capacity
#define THRESHV 0.1
#define BN 128          // nodes per K1 block

// ---------------- workspace layout (bytes) ----------------
#define NPAD 100096
#define LIST_BYTES ((size_t)256 * LCAP * 8)         // u64[256][LCAP] = 8 MiB
#define DBL_OFF    LIST_BYTES
// double indices within the double region:
#define DU    0                   // [128]  W_neigh @ lin_w
#define DR    128                 // [128]  W_root  @ lin_w
#define DV    256                 // [16]   W_edge  @ lin_w
#define DCC   272                 // [256]  per-center |c|^2 (fp64)
#define DROOT 528                 // [NPAD] x . r
#define DA    (528 + NPAD)        // [NPAD] x . u
#define DAGG  (528 + 2*NPAD)      // [NPAD] aggregate (zeroed)
#define DEND  (528 + 3*NPAD)
#define INT_OFF (DBL_OFF + (size_t)DEND * 8)
#define CCT_B   0                 // float2[256] (ccf, T)
#define MASK_B  2048              // u32[3200] in_nb bitmask (zeroed)
#define CNT_B   (2048 + 12800)    // int[256] candidate counters (zeroed)
#define HNB_B   (2048 + 12800 + 1024) // int[256] has_neighbor (zeroed)
#define INT_BYTES (2048 + 12800 + 1024 + 1024)
#define BF_OFF   (INT_OFF + INT_BYTES)              // chi[256*128] + clo[256*128] bf16
#define XX_OFF   (BF_OFF + 2*(size_t)256*128*2)     // float xx[NPAD]
#define ZERO_OFF   (DBL_OFF + (size_t)DAGG * 8)
#define ZERO_BYTES ((size_t)NPAD * 8 + INT_BYTES)   // agg64 + cct + mask + cnt + hnb
#define WS_NEED    (XX_OFF + (size_t)NPAD * 4)

__device__ __forceinline__ float fma4(float4 a, float4 b, float acc) {
  acc = fmaf(a.x, b.x, acc); acc = fmaf(a.y, b.y, acc);
  acc = fmaf(a.z, b.z, acc); acc = fmaf(a.w, b.w, acc);
  return acc;
}

// round-to-nearest-even f32 -> bf16 (finite inputs)
__device__ __forceinline__ short f2bf(float f) {
  u32 u = __float_as_uint(f);
  u32 r = (u + 0x7fffu + ((u >> 16) & 1u)) >> 16;
  return (short)r;
}
__device__ __forceinline__ float bf2f(short h) {
  return __uint_as_float(((u32)(unsigned short)h) << 16);
}

// fp32 d2 (fallback path only; self-consistent within K2)
__device__ float d2f32(const float* __restrict__ center, const float* __restrict__ x,
                       int c, int n, float ccv) {
  float dt = 0.f, xx = 0.f;
  for (int j = 0; j < DD; j += 4) {
    float4 xv = *(const float4*)(x + (size_t)n*DD + j);
    float4 cv = *(const float4*)(center + (size_t)c*DD + j);
    dt = fma4(xv, cv, dt); xx = fma4(xv, xv, xx);
  }
  return (ccv + xx) - 2.0f*dt;
}

// ---------- KA: weights->scalars (fp64), per-center cc/T, center hi/lo bf16 ----------
__global__ void ka_pre(const float* __restrict__ Wr, const float* __restrict__ Wn,
                       const float* __restrict__ We, const float* __restrict__ lw,
                       const float* __restrict__ center,
                       double* __restrict__ dbl, float2* __restrict__ cct,
                       short* __restrict__ chi, short* __restrict__ clo, int M) {
  int t = threadIdx.x;
  if (blockIdx.x == 0) {
    if (t < DD) {
      double su = 0.0, sr = 0.0;
      for (int j = 0; j < DD; ++j) {
        double l = (double)lw[j];
        su = fma((double)Wn[(size_t)t*DD + j], l, su);
        sr = fma((double)Wr[(size_t)t*DD + j], l, sr);
      }
      dbl[DU + t] = su; dbl[DR + t] = sr;
    } else if (t < DD + EAD) {
      int k = t - DD; double sv = 0.0;
      for (int j = 0; j < DD; ++j)
        sv = fma((double)We[(size_t)k*DD + j], (double)lw[j], sv);
      dbl[DV + k] = sv;
    }
  } else {
    if (t < M) {
      double s = 0.0;
      for (int j = 0; j < DD; ++j) {
        float f = center[(size_t)t*DD + j];
        double cv = (double)f;
        s = fma(cv, cv, s);
        short h = f2bf(f);
        chi[(size_t)t*DD + j] = h;
        clo[(size_t)t*DD + j] = f2bf(f - bf2f(h));
      }
      dbl[DCC + t] = s;
      float ccf = (float)s;
      // candidate threshold: mean cc+D, sd = sqrt(2D+4cc); z=2.25 -> ~1200 candidates,
      // far above the top-64 cutoff; K2 fallback covers any miss
      float T = ccf + (float)DD - 2.25f * sqrtf(2.0f*(float)DD + 4.0f*ccf);
      T = fminf(T, R2C);
      cct[t] = make_float2(ccf, T);
    }
  }
}

// ---------- KB: per-node scalars (xx fp32, root/a fp64) ----------
__global__ void kb_node(const float* __restrict__ x, const double* __restrict__ dbl,
                        double* __restrict__ root64, double* __restrict__ a64,
                        float* __restrict__ xxg, int N) {
  int n = blockIdx.x*256 + threadIdx.x;
  if (n >= N) return;
  float xxv = 0.f; double ra = 0.0, aa = 0.0;
  for (int j = 0; j < DD; j += 4) {
    float4 xv = *(const float4*)(x + (size_t)n*DD + j);
    xxv = fma4(xv, xv, xxv);
    const float* pv = (const float*)&xv;
    #pragma unroll
    for (int q = 0; q < 4; ++q) {
      double dx = (double)pv[q];
      ra = fma(dx, dbl[DR + j + q], ra);
      aa = fma(dx, dbl[DU + j + q], aa);
    }
  }
  root64[n] = ra; a64[n] = aa; xxg[n] = xxv;
}

// ---------- K1: bf16-split MFMA distance pass + candidate capture ----------
// LDS tile 16B-slot address: row-stride 64B (32 bf16), slot XOR-swizzle -> each
// wave's 64 lanes read a contiguous 1KB stripe (conflict-free).
__device__ __forceinline__ int a16(int row, int kg) {
  return row*32 + (((kg ^ (row >> 1)) & 3) << 3);   // element (short) index
}

__launch_bounds__(512)
__global__ void k1_mfma(const float* __restrict__ x,
                        const short* __restrict__ chi, const short* __restrict__ clo,
                        const float2* __restrict__ cct, const float* __restrict__ xxg,
                        int* __restrict__ cnt, u64* __restrict__ list, int N) {
  __shared__ __align__(16) short cs_hi[256*32];   // 16 KB
  __shared__ __align__(16) short cs_lo[256*32];   // 16 KB
  __shared__ __align__(16) short xs_hi[128*32];   // 8 KB
  __shared__ __align__(16) short xs_lo[128*32];   // 8 KB

  const int tid = threadIdx.x;
  const int bn = blockIdx.x * BN;
  const int wid = tid >> 6, l = tid & 63, r16 = l & 15, kg = l >> 4;
  const int wc = wid >> 1, wn = wid & 1;          // 4 center-strips x 2 node-strips

  f32x4 acc[4][4];
  #pragma unroll
  for (int tc = 0; tc < 4; ++tc)
    #pragma unroll
    for (int tn = 0; tn < 4; ++tn)
      acc[tc][tn] = (f32x4){0.f, 0.f, 0.f, 0.f};

  const int xrow = tid >> 2, xpart = tid & 3;     // x-staging assignment
  const int xgn = bn + xrow;

  for (int kc = 0; kc < 4; ++kc) {
    // --- stage centers hi/lo (pre-converted bf16, global->LDS swizzled) ---
    #pragma unroll
    for (int t = 0; t < 4; ++t) {
      const int rem = ((t & 1) << 9) + tid;       // 0..1023
      const int row = rem >> 2, kgs = rem & 3;
      const short* src = (t < 2 ? chi : clo) + (size_t)row*DD + kc*32 + kgs*8;
      short* dst = (t < 2 ? cs_hi : cs_lo);
      *(bf16x8*)&dst[a16(row, kgs)] = *(const bf16x8*)src;
    }
    // --- stage x tile: load f32, split hi/lo, write swizzled ---
    {
      float4 v0 = make_float4(0.f,0.f,0.f,0.f), v1 = v0;
      if (xgn < N) {
        v0 = *(const float4*)(x + (size_t)xgn*DD + kc*32 + xpart*8);
        v1 = *(const float4*)(x + (size_t)xgn*DD + kc*32 + xpart*8 + 4);
      }
      union { short s[8]; bf16x8 v; } hi, lo;
      const float* pv0 = (const float*)&v0;
      const float* pv1 = (const float*)&v1;
      #pragma unroll
      for (int q = 0; q < 4; ++q) {
        short h0 = f2bf(pv0[q]); hi.s[q]   = h0; lo.s[q]   = f2bf(pv0[q] - bf2f(h0));
        short h1 = f2bf(pv1[q]); hi.s[q+4] = h1; lo.s[q+4] = f2bf(pv1[q] - bf2f(h1));
      }
      *(bf16x8*)&xs_hi[a16(xrow, xpart)] = hi.v;
      *(bf16x8*)&xs_lo[a16(xrow, xpart)] = lo.v;
    }
    __syncthreads();

    // --- fragments + MFMA (3-term bf16 split) ---
    bf16x8 ah[4], al[4];
    #pragma unroll
    for (int tc = 0; tc < 4; ++tc) {
      const int rc = wc*64 + tc*16 + r16;
      ah[tc] = *(bf16x8*)&cs_hi[a16(rc, kg)];
      al[tc] = *(bf16x8*)&cs_lo[a16(rc, kg)];
    }
    #pragma unroll
    for (int tn = 0; tn < 4; ++tn) {
      const int rn = wn*64 + tn*16 + r16;
      bf16x8 bh = *(bf16x8*)&xs_hi[a16(rn, kg)];
      bf16x8 bl = *(bf16x8*)&xs_lo[a16(rn, kg)];
      #pragma unroll
      for (int tc = 0; tc < 4; ++tc) {
        acc[tc][tn] = __builtin_amdgcn_mfma_f32_16x16x32_bf16(ah[tc], bh, acc[tc][tn], 0, 0, 0);
        acc[tc][tn] = __builtin_amdgcn_mfma_f32_16x16x32_bf16(ah[tc], bl, acc[tc][tn], 0, 0, 0);
        acc[tc][tn] = __builtin_amdgcn_mfma_f32_16x16x32_bf16(al[tc], bh, acc[tc][tn], 0, 0, 0);
      }
    }
    __syncthreads();
  }

  // --- capture: D layout col=lane&15 (node), row=(lane>>4)*4+q (center) ---
  #pragma unroll
  for (int tn = 0; tn < 4; ++tn) {
    const int gn = bn + wn*64 + tn*16 + r16;
    if (gn >= N) continue;
    const float xv = xxg[gn];
    #pragma unroll
    for (int tc = 0; tc < 4; ++tc) {
      #pragma unroll
      for (int q = 0; q < 4; ++q) {
        const int c = wc*64 + tc*16 + kg*4 + q;
        const float2 ct = cct[c];
        const float val = (ct.x + xv) - 2.0f * acc[tc][tn][q];
        if (val <= ct.y) {
          int slot = atomicAdd(&cnt[c], 1);
          if (slot < LCAP)
            list[(size_t)c*LCAP + slot] = ((u64)__float_as_uint(val) << 32) | (u32)gn;
        }
      }
    }
  }
}

// ---------- K2: exact per-center top-64 (fp64 re-rank of candidates) ----------
__launch_bounds__(256)
__global__ void k2_sel(const float* __restrict__ x, const float* __restrict__ center,
                       const double* __restrict__ dbl, const float2* __restrict__ cct,
                       u32* __restrict__ mask, int* __restrict__ hnb,
                       const u64* __restrict__ list, const int* __restrict__ cnt, int N) {
  const int c = blockIdx.x, tid = threadIdx.x;
  __shared__ u32 hist[NBINS];
  __shared__ double dval[CANDCAP];
  __shared__ int    dnode[CANDCAP];
  __shared__ u32 spart[256];
  __shared__ int shW, shB, shQ;

  for (int i = tid; i < NBINS; i += 256) hist[i] = 0u;
  if (tid == 0) { shW = 0; shB = 0x7ffffff; shQ = 0; }
  __syncthreads();

  const float2 ct = cct[c];
  const int C = cnt[c];
  const bool fast = (C >= 64 && C <= LCAP);
  const float bscale = (float)NBINS / R2C;

  if (fast) {
    for (int i = tid; i < C; i += 256) {
      float val = __uint_as_float((u32)(list[(size_t)c*LCAP + i] >> 32));
      int b = (int)(val * bscale); b = min(NBINS-1, max(0, b));
      atomicAdd(&hist[b], 1u);
    }
  } else {
    int w = 0;
    for (int n = tid; n < N; n += 256) {
      float val = d2f32(center, x, c, n, ct.x);
      if (val <= R2C) {
        ++w;
        int b = (int)(val * bscale); b = min(NBINS-1, max(0, b));
        atomicAdd(&hist[b], 1u);
      }
    }
    atomicAdd(&shW, w);
  }
  __syncthreads();
  const int W = fast ? 0x7fffffff : shW;
  if (W == 0) return;                  // has_nb stays 0
  const int Rk = min(64, W);

  // block-wide scan of hist -> first bin B with cum >= Rk
  u32 loc[16]; u32 psum = 0;
  const int b0 = tid * 16;
  #pragma unroll
  for (int k = 0; k < 16; ++k) { loc[k] = hist[b0 + k]; psum += loc[k]; }
  spart[tid] = psum; __syncthreads();
  for (int off = 1; off < 256; off <<= 1) {
    u32 vv = (tid >= off) ? spart[tid - off] : 0u;
    __syncthreads(); spart[tid] += vv; __syncthreads();
  }
  u32 run = spart[tid] - psum;
  int Bl = 0x7ffffff;
  #pragma unroll
  for (int k = 0; k < 16; ++k) { run += loc[k]; if ((int)run >= Rk && Bl == 0x7ffffff) Bl = b0 + k; }
  if (Bl != 0x7ffffff) atomicMin(&shB, Bl);
  __syncthreads();
  const int Bcol = min(shB + 2, NBINS - 1);  // +2 bins slack >> bf16-split noise

  // collect candidate nodes with bin <= Bcol
  if (fast) {
    for (int i = tid; i < C; i += 256) {
      u64 e = list[(size_t)c*LCAP + i];
      float val = __uint_as_float((u32)(e >> 32));
      int b = (int)(val * bscale); b = min(NBINS-1, max(0, b));
      if (b <= Bcol) { int s = atomicAdd(&shQ, 1); if (s < CANDCAP) dnode[s] = (int)(u32)e; }
    }
  } else {
    for (int n = tid; n < N; n += 256) {
      float val = d2f32(center, x, c, n, ct.x);
      if (val <= R2C) {
        int b = (int)(val * bscale); b = min(NBINS-1, max(0, b));
        if (b <= Bcol) { int s = atomicAdd(&shQ, 1); if (s < CANDCAP) dnode[s] = n; }
      }
    }
  }
  __syncthreads();
  const int Q = min(shQ, CANDCAP);

  // fp64 re-rank: exact values for collected candidates
  const double ccd = dbl[DCC + c];
  for (int i = tid; i < Q; i += 256) {
    int n = dnode[i];
    double dt = 0.0, xx = 0.0;
    for (int j = 0; j < DD; ++j) {
      double dx = (double)x[(size_t)n*DD + j];
      dt = fma(dx, (double)center[(size_t)c*DD + j], dt);
      xx = fma(dx, dx, xx);
    }
    dval[i] = (ccd + xx) - 2.0*dt;
  }
  __syncthreads();

  // exact rank-select: keep rank < Rk under (val, node) lexicographic order
  for (int i = tid; i < Q; i += 256) {
    double vi = dval[i]; int ni = dnode[i];
    int rank = 0;
    for (int j = 0; j < Q; ++j) {
      double vj = dval[j];
      rank += (vj < vi) || (vj == vi && dnode[j] < ni);
    }
    if (rank < Rk) atomicOr(&mask[(u32)ni >> 5], 1u << (ni & 31));
  }
  if (tid == 0) hnb[c] = 1;
}

// ---------- K3: edge pass (fp64 scalar messages, edge_attr read only when kept) ----------
__global__ void k3_edge(const int* __restrict__ ei, const float* __restrict__ eattr,
                        const double* __restrict__ dbl, const u32* __restrict__ mask,
                        double* __restrict__ agg, const double* __restrict__ a64, int E) {
  int e = blockIdx.x*256 + threadIdx.x;
  if (e >= E) return;
  int s = ei[e], d = ei[E + e];
  u32 ks = (mask[(u32)s >> 5] >> (s & 31)) & 1u;
  u32 kd = (mask[(u32)d >> 5] >> (d & 31)) & 1u;
  if (!(ks & kd)) return;
  const float* ep = eattr + (size_t)e * EAD;
  double ea = 0.0;
  #pragma unroll
  for (int k = 0; k < EAD; ++k) ea = fma((double)ep[k], dbl[DV + k], ea);
  atomicAdd(&agg[d], a64[s] + ea);
}

// ---------- K4: gate + int32 output ----------
__global__ void k4_out(const double* __restrict__ root64, const double* __restrict__ agg64,
                       const u32* __restrict__ mask, const int* __restrict__ hnb,
                       const float* __restrict__ lb, int* __restrict__ out, int N, int M) {
  int n = blockIdx.x*256 + threadIdx.x;
  if (n >= N) return;
  double pre = root64[n] + agg64[n] + (double)lb[0];
  bool selb = ((mask[n >> 5] >> (n & 31)) & 1u) != 0u;
  if (!selb && n < M) selb = hnb[n] != 0;
  out[n] = (selb && pre > THRESHV) ? 1 : 0;
}

extern "C" void kernel_launch(void* const* d_in, const int* in_sizes, int n_in,
                              void* d_out, int out_size, void* d_ws, size_t ws_size,
                              hipStream_t stream) {
  const float* x      = (const float*)d_in[0];
  const int*   ei     = (const int*)d_in[1];
  const float* eattr  = (const float*)d_in[2];
  const float* center = (const float*)d_in[3];
  const float* Wr     = (const float*)d_in[4];
  const float* Wn     = (const float*)d_in[5];
  const float* We     = (const float*)d_in[6];
  const float* lw     = (const float*)d_in[7];
  const float* lb     = (const float*)d_in[8];
  int* out = (int*)d_out;

  char* wsb = (char*)d_ws;
  u64*    list   = (u64*)(wsb);
  double* dbl    = (double*)(wsb + DBL_OFF);
  float2* cct    = (float2*)(wsb + INT_OFF + CCT_B);
  u32*    mask   = (u32*)(wsb + INT_OFF + MASK_B);
  int*    cnt    = (int*)(wsb + INT_OFF + CNT_B);
  int*    hnb    = (int*)(wsb + INT_OFF + HNB_B);
  short*  chi    = (short*)(wsb + BF_OFF);
  short*  clo    = chi + (size_t)256*DD;
  float*  xxg    = (float*)(wsb + XX_OFF);
  double* root64 = dbl + DROOT;
  double* a64    = dbl + DA;
  double* agg64  = dbl + DAGG;

  const int N = in_sizes[0] / DD;      // 100000
  const int E = in_sizes[1] / 2;       // 1000000
  const int M = in_sizes[3] / DD;      // 256
  if (N > NPAD || M != 256 || ws_size < WS_NEED) return;
  (void)n_in; (void)out_size;

  // zero agg64 + mask + cnt + hnb (contiguous; cct rewritten by ka_pre)
  hipMemsetAsync(wsb + ZERO_OFF, 0, ZERO_BYTES, stream);

  ka_pre<<<2, 256, 0, stream>>>(Wr, Wn, We, lw, center, dbl, cct, chi, clo, M);
  kb_node<<<(N + 255)/256, 256, 0, stream>>>(x, dbl, root64, a64, xxg, N);
  k1_mfma<<<(N + BN - 1)/BN, 512, 0, stream>>>(x, chi, clo, cct, xxg, cnt, list, N);
  k2_sel<<<M, 256, 0, stream>>>(x, center, dbl, cct, mask, hnb, list, cnt, N);
  k3_edge<<<(E + 255)/256, 256, 0, stream>>>(ei, eattr, dbl, mask, agg64, a64, E);
  k4_out<<<(N + 255)/256, 256, 0, stream>>>(root64, agg64, mask, hnb, lb, out, N, M);
}

// Round 5
// 259.318 us; speedup vs baseline: 3.1565x; 1.6429x over previous
//
#include <hip/hip_runtime.h>
#include <stdint.h>

typedef unsigned long long u64;
typedef unsigned int u32;
typedef unsigned short u16;
typedef __attribute__((ext_vector_type(8))) short bf16x8;
typedef __attribute__((ext_vector_type(4))) float f32x4;

#define DD 128          // node_dim
#define EAD 16          // edge_attr dim
#define R2C 272.25f     // RADIUS^2
#define NBINS 4096
#define CAPB 16         // per-(center,block) candidate capacity
#define CANDCAP 512     // per-center collected-candidate capacity in K2
#define THRESHV 0.1
#define BN 128          // nodes per K1 block

// ---------------- workspace layout (bytes) ----------------
#define NPAD 100096
#define NBLKMAX 800
#define L32_BYTES ((size_t)256 * NBLKMAX * CAPB * 4)   // 13.1 MB
#define CNTB_OFF  L32_BYTES
#define CNTB_BYTES ((size_t)256 * NBLKMAX * 2)         // 400 KB
#define DBL_OFF   (CNTB_OFF + CNTB_BYTES)
// double indices within the double region:
#define DU    0                   // [128]  W_neigh @ lin_w
#define DR    128                 // [128]  W_root  @ lin_w
#define DV    256                 // [16]   W_edge  @ lin_w
#define DCC   272                 // [256]  per-center |c|^2 (fp64)
#define DROOT 528                 // [NPAD] x . r
#define DA    (528 + NPAD)        // [NPAD] x . u
#define DAGG  (528 + 2*NPAD)      // [NPAD] aggregate (zeroed)
#define DEND  (528 + 3*NPAD)
#define INT_OFF (DBL_OFF + (size_t)DEND * 8)
#define CCT_B   0                 // float2[256] (ccf, T)
#define MASK_B  2048              // u32[3200] in_nb bitmask (zeroed)
#define HNB_B   (2048 + 12800)    // int[256] has_neighbor (zeroed)
#define OVF_B   (2048 + 12800 + 1024) // u32[256] overflow flags (zeroed)
#define INT_BYTES (2048 + 12800 + 1024 + 1024)
#define BF_OFF   (INT_OFF + INT_BYTES)              // chi[256*128] + clo[256*128] bf16
#define XX_OFF   (BF_OFF + 2*(size_t)256*128*2)     // float xx[NPAD]
#define ZERO_OFF   (DBL_OFF + (size_t)DAGG * 8)
#define ZERO_BYTES ((size_t)NPAD * 8 + INT_BYTES)   // agg64 + cct + mask + hnb + ovf
#define WS_NEED    (XX_OFF + (size_t)NPAD * 4)

__device__ __forceinline__ float fma4(float4 a, float4 b, float acc) {
  acc = fmaf(a.x, b.x, acc); acc = fmaf(a.y, b.y, acc);
  acc = fmaf(a.z, b.z, acc); acc = fmaf(a.w, b.w, acc);
  return acc;
}

// round-to-nearest-even f32 -> bf16 (finite inputs)
__device__ __forceinline__ short f2bf(float f) {
  u32 u = __float_as_uint(f);
  u32 r = (u + 0x7fffu + ((u >> 16) & 1u)) >> 16;
  return (short)r;
}
__device__ __forceinline__ float bf2f(short h) {
  return __uint_as_float(((u32)(unsigned short)h) << 16);
}

// fp32 d2 (fallback path only; self-consistent within K2)
__device__ float d2f32(const float* __restrict__ center, const float* __restrict__ x,
                       int c, int n, float ccv) {
  float dt = 0.f, xx = 0.f;
  for (int j = 0; j < DD; j += 4) {
    float4 xv = *(const float4*)(x + (size_t)n*DD + j);
    float4 cv = *(const float4*)(center + (size_t)c*DD + j);
    dt = fma4(xv, cv, dt); xx = fma4(xv, xv, xx);
  }
  return (ccv + xx) - 2.0f*dt;
}

// ---------- KA: weights->scalars (fp64), per-center cc/T, center hi/lo bf16 ----------
__global__ void ka_pre(const float* __restrict__ Wr, const float* __restrict__ Wn,
                       const float* __restrict__ We, const float* __restrict__ lw,
                       const float* __restrict__ center,
                       double* __restrict__ dbl, float2* __restrict__ cct,
                       short* __restrict__ chi, short* __restrict__ clo, int M) {
  int t = threadIdx.x;
  if (blockIdx.x == 0) {
    if (t < DD) {
      double su = 0.0, sr = 0.0;
      for (int j = 0; j < DD; ++j) {
        double l = (double)lw[j];
        su = fma((double)Wn[(size_t)t*DD + j], l, su);
        sr = fma((double)Wr[(size_t)t*DD + j], l, sr);
      }
      dbl[DU + t] = su; dbl[DR + t] = sr;
    } else if (t < DD + EAD) {
      int k = t - DD; double sv = 0.0;
      for (int j = 0; j < DD; ++j)
        sv = fma((double)We[(size_t)k*DD + j], (double)lw[j], sv);
      dbl[DV + k] = sv;
    }
  } else {
    if (t < M) {
      double s = 0.0;
      for (int j = 0; j < DD; ++j) {
        float f = center[(size_t)t*DD + j];
        double cv = (double)f;
        s = fma(cv, cv, s);
        short h = f2bf(f);
        chi[(size_t)t*DD + j] = h;
        clo[(size_t)t*DD + j] = f2bf(f - bf2f(h));
      }
      dbl[DCC + t] = s;
      float ccf = (float)s;
      // candidate threshold: mean cc+D, sd = sqrt(2D+4cc); z=2.25 -> ~1200 candidates,
      // far above the top-64 cutoff; K2 fallback covers any miss
      float T = ccf + (float)DD - 2.25f * sqrtf(2.0f*(float)DD + 4.0f*ccf);
      T = fminf(T, R2C);
      cct[t] = make_float2(ccf, T);
    }
  }
}

// ---------- KB: per-node scalars (xx fp32, root/a fp64) ----------
__global__ void kb_node(const float* __restrict__ x, const double* __restrict__ dbl,
                        double* __restrict__ root64, double* __restrict__ a64,
                        float* __restrict__ xxg, int N) {
  int n = blockIdx.x*256 + threadIdx.x;
  if (n >= N) return;
  float xxv = 0.f; double ra = 0.0, aa = 0.0;
  for (int j = 0; j < DD; j += 4) {
    float4 xv = *(const float4*)(x + (size_t)n*DD + j);
    xxv = fma4(xv, xv, xxv);
    const float* pv = (const float*)&xv;
    #pragma unroll
    for (int q = 0; q < 4; ++q) {
      double dx = (double)pv[q];
      ra = fma(dx, dbl[DR + j + q], ra);
      aa = fma(dx, dbl[DU + j + q], aa);
    }
  }
  root64[n] = ra; a64[n] = aa; xxg[n] = xxv;
}

// ---------- K1: bf16-split MFMA distance pass, LDS-aggregated capture ----------
// LDS tile 16B-slot address: row-stride 64B (32 bf16), slot XOR-swizzle -> each
// wave's 64 lanes read a contiguous 1KB stripe (conflict-free).
__device__ __forceinline__ int a16(int row, int kg) {
  return row*32 + (((kg ^ (row >> 1)) & 3) << 3);   // element (short) index
}

__launch_bounds__(512)
__global__ void k1_mfma(const float* __restrict__ x,
                        const short* __restrict__ chi, const short* __restrict__ clo,
                        const float2* __restrict__ cct, const float* __restrict__ xxg,
                        u32* __restrict__ list32, u16* __restrict__ cntb,
                        u32* __restrict__ ovf, int N, int NBLK) {
  __shared__ __align__(16) char smem[49152];        // 48 KB
  short* cs_hi = (short*)smem;                      // 16 KB
  short* cs_lo = (short*)(smem + 16384);            // 16 KB
  short* xs_hi = (short*)(smem + 32768);            // 8 KB
  short* xs_lo = (short*)(smem + 40960);            // 8 KB
  u32* cap_cnt = (u32*)smem;                        // overlay after compute: [256]
  u32* cap_buf = (u32*)(smem + 1024);               // overlay: [256*CAPB] = 16 KB

  const int tid = threadIdx.x;
  const int blk = blockIdx.x;
  const int bn = blk * BN;
  const int wid = tid >> 6, l = tid & 63, r16 = l & 15, kg = l >> 4;
  const int wc = wid >> 1, wn = wid & 1;            // 4 center-strips x 2 node-strips

  f32x4 acc[4][4];
  #pragma unroll
  for (int tc = 0; tc < 4; ++tc)
    #pragma unroll
    for (int tn = 0; tn < 4; ++tn)
      acc[tc][tn] = (f32x4){0.f, 0.f, 0.f, 0.f};

  const int xrow = tid >> 2, xpart = tid & 3;       // x-staging assignment
  const int xgn = bn + xrow;

  for (int kc = 0; kc < 4; ++kc) {
    // --- stage centers hi/lo (pre-converted bf16, global->LDS swizzled) ---
    #pragma unroll
    for (int t = 0; t < 4; ++t) {
      const int rem = ((t & 1) << 9) + tid;         // 0..1023
      const int row = rem >> 2, kgs = rem & 3;
      const short* src = (t < 2 ? chi : clo) + (size_t)row*DD + kc*32 + kgs*8;
      short* dst = (t < 2 ? cs_hi : cs_lo);
      *(bf16x8*)&dst[a16(row, kgs)] = *(const bf16x8*)src;
    }
    // --- stage x tile: load f32, split hi/lo, write swizzled ---
    {
      float4 v0 = make_float4(0.f,0.f,0.f,0.f), v1 = v0;
      if (xgn < N) {
        v0 = *(const float4*)(x + (size_t)xgn*DD + kc*32 + xpart*8);
        v1 = *(const float4*)(x + (size_t)xgn*DD + kc*32 + xpart*8 + 4);
      }
      union { short s[8]; bf16x8 v; } hi, lo;
      const float* pv0 = (const float*)&v0;
      const float* pv1 = (const float*)&v1;
      #pragma unroll
      for (int q = 0; q < 4; ++q) {
        short h0 = f2bf(pv0[q]); hi.s[q]   = h0; lo.s[q]   = f2bf(pv0[q] - bf2f(h0));
        short h1 = f2bf(pv1[q]); hi.s[q+4] = h1; lo.s[q+4] = f2bf(pv1[q] - bf2f(h1));
      }
      *(bf16x8*)&xs_hi[a16(xrow, xpart)] = hi.v;
      *(bf16x8*)&xs_lo[a16(xrow, xpart)] = lo.v;
    }
    __syncthreads();

    // --- fragments + MFMA (3-term bf16 split) ---
    bf16x8 ah[4], al[4];
    #pragma unroll
    for (int tc = 0; tc < 4; ++tc) {
      const int rc = wc*64 + tc*16 + r16;
      ah[tc] = *(bf16x8*)&cs_hi[a16(rc, kg)];
      al[tc] = *(bf16x8*)&cs_lo[a16(rc, kg)];
    }
    #pragma unroll
    for (int tn = 0; tn < 4; ++tn) {
      const int rn = wn*64 + tn*16 + r16;
      bf16x8 bh = *(bf16x8*)&xs_hi[a16(rn, kg)];
      bf16x8 bl = *(bf16x8*)&xs_lo[a16(rn, kg)];
      #pragma unroll
      for (int tc = 0; tc < 4; ++tc) {
        acc[tc][tn] = __builtin_amdgcn_mfma_f32_16x16x32_bf16(ah[tc], bh, acc[tc][tn], 0, 0, 0);
        acc[tc][tn] = __builtin_amdgcn_mfma_f32_16x16x32_bf16(ah[tc], bl, acc[tc][tn], 0, 0, 0);
        acc[tc][tn] = __builtin_amdgcn_mfma_f32_16x16x32_bf16(al[tc], bh, acc[tc][tn], 0, 0, 0);
      }
    }
    __syncthreads();
  }

  // --- capture into LDS (no global atomics) ---
  if (tid < 256) cap_cnt[tid] = 0;
  __syncthreads();

  const float bscale = (float)NBINS / R2C;
  // D layout: col=lane&15 (node), row=(lane>>4)*4+q (center)
  #pragma unroll
  for (int tn = 0; tn < 4; ++tn) {
    const int gn = bn + wn*64 + tn*16 + r16;
    if (gn >= N) continue;
    const float xv = xxg[gn];
    #pragma unroll
    for (int tc = 0; tc < 4; ++tc) {
      #pragma unroll
      for (int q = 0; q < 4; ++q) {
        const int c = wc*64 + tc*16 + kg*4 + q;
        const float2 ct = cct[c];
        const float val = (ct.x + xv) - 2.0f * acc[tc][tn][q];
        if (val <= ct.y) {
          int b = (int)(val * bscale); b = min(NBINS-1, max(0, b));
          u32 slot = atomicAdd(&cap_cnt[c], 1u);
          if (slot < CAPB) cap_buf[c*CAPB + slot] = ((u32)b << 17) | (u32)gn;
        }
      }
    }
  }
  __syncthreads();

  // write per-(center,block) counts + entries (deterministic slots, no contention)
  if (tid < 256) {
    u32 cc = cap_cnt[tid];
    if (cc > CAPB) { atomicOr(&ovf[tid], 1u); cc = CAPB; }
    cntb[(size_t)tid*NBLK + blk] = (u16)cc;
  }
  for (int i = tid; i < 256*CAPB; i += 512) {
    const int c = i >> 4, j = i & (CAPB-1);
    list32[((size_t)c*NBLK + blk)*CAPB + j] = cap_buf[i];
  }
}

// ---------- K2: exact per-center top-64 (fp64 re-rank of candidates) ----------
__launch_bounds__(256)
__global__ void k2_sel(const float* __restrict__ x, const float* __restrict__ center,
                       const double* __restrict__ dbl, const float2* __restrict__ cct,
                       u32* __restrict__ mask, int* __restrict__ hnb,
                       const u32* __restrict__ list32, const u16* __restrict__ cntb,
                       const u32* __restrict__ ovf, int N, int NBLK) {
  const int c = blockIdx.x, tid = threadIdx.x;
  __shared__ u32 hist[NBINS];
  __shared__ double dval[CANDCAP];
  __shared__ int    dnode[CANDCAP];
  __shared__ u32 spart[256];
  __shared__ int shW, shB, shQ;

  for (int i = tid; i < NBINS; i += 256) hist[i] = 0u;
  if (tid == 0) { shW = 0; shB = 0x7ffffff; shQ = 0; }
  __syncthreads();

  const float2 ct = cct[c];
  const bool ovfc = (ovf[c] != 0u);
  const float bscale = (float)NBINS / R2C;

  if (!ovfc) {
    int csum = 0;
    for (int blk = tid; blk < NBLK; blk += 256) {
      const int cc = cntb[(size_t)c*NBLK + blk];
      csum += cc;
      const size_t base = ((size_t)c*NBLK + blk)*CAPB;
      for (int j = 0; j < cc; ++j) atomicAdd(&hist[list32[base + j] >> 17], 1u);
    }
    atomicAdd(&shW, csum);
  }
  __syncthreads();
  int C = shW;
  const bool fast = !ovfc && (C >= 64);

  if (!fast) {
    // exact fallback: full fp32 rescan of this center's row (hist rebuilt)
    for (int i = tid; i < NBINS; i += 256) hist[i] = 0u;
    if (tid == 0) shW = 0;
    __syncthreads();
    int w = 0;
    for (int n = tid; n < N; n += 256) {
      float val = d2f32(center, x, c, n, ct.x);
      if (val <= R2C) {
        ++w;
        int b = (int)(val * bscale); b = min(NBINS-1, max(0, b));
        atomicAdd(&hist[b], 1u);
      }
    }
    atomicAdd(&shW, w);
    __syncthreads();
    C = shW;
    if (C == 0) return;                // has_nb stays 0
  }
  const int Rk = min(64, C);

  // block-wide scan of hist -> first bin B with cum >= Rk
  u32 loc[16]; u32 psum = 0;
  const int b0 = tid * 16;
  #pragma unroll
  for (int k = 0; k < 16; ++k) { loc[k] = hist[b0 + k]; psum += loc[k]; }
  spart[tid] = psum; __syncthreads();
  for (int off = 1; off < 256; off <<= 1) {
    u32 vv = (tid >= off) ? spart[tid - off] : 0u;
    __syncthreads(); spart[tid] += vv; __syncthreads();
  }
  u32 run = spart[tid] - psum;
  int Bl = 0x7ffffff;
  #pragma unroll
  for (int k = 0; k < 16; ++k) { run += loc[k]; if ((int)run >= Rk && Bl == 0x7ffffff) Bl = b0 + k; }
  if (Bl != 0x7ffffff) atomicMin(&shB, Bl);
  __syncthreads();
  const int Bcol = min(shB + 2, NBINS - 1);  // +2 bins slack >> bf16-split/fp32 noise

  // collect candidate nodes with bin <= Bcol
  if (fast) {
    for (int blk = tid; blk < NBLK; blk += 256) {
      const int cc = cntb[(size_t)c*NBLK + blk];
      const size_t base = ((size_t)c*NBLK + blk)*CAPB;
      for (int j = 0; j < cc; ++j) {
        const u32 e = list32[base + j];
        if ((int)(e >> 17) <= Bcol) {
          int s = atomicAdd(&shQ, 1);
          if (s < CANDCAP) dnode[s] = (int)(e & 0x1FFFFu);
        }
      }
    }
  } else {
    for (int n = tid; n < N; n += 256) {
      float val = d2f32(center, x, c, n, ct.x);
      if (val <= R2C) {
        int b = (int)(val * bscale); b = min(NBINS-1, max(0, b));
        if (b <= Bcol) { int s = atomicAdd(&shQ, 1); if (s < CANDCAP) dnode[s] = n; }
      }
    }
  }
  __syncthreads();
  const int Q = min(shQ, CANDCAP);

  // fp64 re-rank: exact values for collected candidates
  const double ccd = dbl[DCC + c];
  for (int i = tid; i < Q; i += 256) {
    int n = dnode[i];
    double dt = 0.0, xx = 0.0;
    #pragma unroll 4
    for (int j = 0; j < DD; ++j) {
      double dx = (double)x[(size_t)n*DD + j];
      dt = fma(dx, (double)center[(size_t)c*DD + j], dt);
      xx = fma(dx, dx, xx);
    }
    dval[i] = (ccd + xx) - 2.0*dt;
  }
  __syncthreads();

  // exact rank-select: keep rank < Rk under (val, node) lexicographic order
  for (int i = tid; i < Q; i += 256) {
    double vi = dval[i]; int ni = dnode[i];
    int rank = 0;
    for (int j = 0; j < Q; ++j) {
      double vj = dval[j];
      rank += (vj < vi) || (vj == vi && dnode[j] < ni);
    }
    if (rank < Rk) atomicOr(&mask[(u32)ni >> 5], 1u << (ni & 31));
  }
  if (tid == 0) hnb[c] = 1;
}

// ---------- K3: edge pass (fp64 scalar messages, edge_attr read only when kept) ----------
__global__ void k3_edge(const int* __restrict__ ei, const float* __restrict__ eattr,
                        const double* __restrict__ dbl, const u32* __restrict__ mask,
                        double* __restrict__ agg, const double* __restrict__ a64, int E) {
  int e = blockIdx.x*256 + threadIdx.x;
  if (e >= E) return;
  int s = ei[e], d = ei[E + e];
  u32 ks = (mask[(u32)s >> 5] >> (s & 31)) & 1u;
  u32 kd = (mask[(u32)d >> 5] >> (d & 31)) & 1u;
  if (!(ks & kd)) return;
  const float* ep = eattr + (size_t)e * EAD;
  double ea = 0.0;
  #pragma unroll
  for (int k = 0; k < EAD; ++k) ea = fma((double)ep[k], dbl[DV + k], ea);
  atomicAdd(&agg[d], a64[s] + ea);
}

// ---------- K4: gate + int32 output ----------
__global__ void k4_out(const double* __restrict__ root64, const double* __restrict__ agg64,
                       const u32* __restrict__ mask, const int* __restrict__ hnb,
                       const float* __restrict__ lb, int* __restrict__ out, int N, int M) {
  int n = blockIdx.x*256 + threadIdx.x;
  if (n >= N) return;
  double pre = root64[n] + agg64[n] + (double)lb[0];
  bool selb = ((mask[n >> 5] >> (n & 31)) & 1u) != 0u;
  if (!selb && n < M) selb = hnb[n] != 0;
  out[n] = (selb && pre > THRESHV) ? 1 : 0;
}

extern "C" void kernel_launch(void* const* d_in, const int* in_sizes, int n_in,
                              void* d_out, int out_size, void* d_ws, size_t ws_size,
                              hipStream_t stream) {
  const float* x      = (const float*)d_in[0];
  const int*   ei     = (const int*)d_in[1];
  const float* eattr  = (const float*)d_in[2];
  const float* center = (const float*)d_in[3];
  const float* Wr     = (const float*)d_in[4];
  const float* Wn     = (const float*)d_in[5];
  const float* We     = (const float*)d_in[6];
  const float* lw     = (const float*)d_in[7];
  const float* lb     = (const float*)d_in[8];
  int* out = (int*)d_out;

  char* wsb = (char*)d_ws;
  u32*    list32 = (u32*)(wsb);
  u16*    cntb   = (u16*)(wsb + CNTB_OFF);
  double* dbl    = (double*)(wsb + DBL_OFF);
  float2* cct    = (float2*)(wsb + INT_OFF + CCT_B);
  u32*    mask   = (u32*)(wsb + INT_OFF + MASK_B);
  int*    hnb    = (int*)(wsb + INT_OFF + HNB_B);
  u32*    ovf    = (u32*)(wsb + INT_OFF + OVF_B);
  short*  chi    = (short*)(wsb + BF_OFF);
  short*  clo    = chi + (size_t)256*DD;
  float*  xxg    = (float*)(wsb + XX_OFF);
  double* root64 = dbl + DROOT;
  double* a64    = dbl + DA;
  double* agg64  = dbl + DAGG;

  const int N = in_sizes[0] / DD;      // 100000
  const int E = in_sizes[1] / 2;       // 1000000
  const int M = in_sizes[3] / DD;      // 256
  const int NBLK = (N + BN - 1) / BN;  // 782
  if (N > NPAD || M != 256 || NBLK > NBLKMAX || ws_size < WS_NEED) return;
  (void)n_in; (void)out_size;

  // zero agg64 + cct + mask + hnb + ovf (contiguous; cct rewritten by ka_pre);
  // cntb needs no init (written unconditionally by k1 for all blk < NBLK)
  hipMemsetAsync(wsb + ZERO_OFF, 0, ZERO_BYTES, stream);

  ka_pre<<<2, 256, 0, stream>>>(Wr, Wn, We, lw, center, dbl, cct, chi, clo, M);
  kb_node<<<(N + 255)/256, 256, 0, stream>>>(x, dbl, root64, a64, xxg, N);
  k1_mfma<<<NBLK, 512, 0, stream>>>(x, chi, clo, cct, xxg, list32, cntb, ovf, N, NBLK);
  k2_sel<<<M, 256, 0, stream>>>(x, center, dbl, cct, mask, hnb, list32, cntb, ovf, N, NBLK);
  k3_edge<<<(E + 255)/256, 256, 0, stream>>>(ei, eattr, dbl, mask, agg64, a64, E);
  k4_out<<<(N + 255)/256, 256, 0, stream>>>(root64, agg64, mask, hnb, lb, out, N, M);
}